// Round 1
// baseline (258.522 us; speedup 1.0000x reference)
//
#include <hip/hip_runtime.h>
#include <hip/hip_bf16.h>

#define N_NODES 50000
#define N_EDGES 600000
#define D_IN 256
#define D 128

#define SCAN_CHUNK 1024
#define N_CHUNKS ((N_NODES + SCAN_CHUNK - 1) / SCAN_CHUNK)  // 49
#define GEMM_BLOCKS ((N_NODES + 31) / 32)                   // 1563
#define EDGE_BLOCKS ((N_EDGES + 255) / 256)                 // 2344

typedef unsigned short ushort_t;
typedef __attribute__((ext_vector_type(8))) short bf16x8;
typedef __attribute__((ext_vector_type(16))) float f32x16;

__device__ __forceinline__ float bf2f(ushort_t u) {
  union { unsigned int i; float f; } v;
  v.i = ((unsigned int)u) << 16;
  return v.f;
}
__device__ __forceinline__ ushort_t f2bf(float f) {
  union { float f; unsigned int i; } v;
  v.f = f;
  unsigned int x = v.i;
  unsigned int r = (x + 0x7FFFu + ((x >> 16) & 1u)) >> 16;  // RNE
  return (ushort_t)r;
}

// Swizzled-W addressing: element (j,k) of [128,KDIM] W, hi/lo split:
//   wv=j>>5, fm=j&31, kh=k>>7, t=(k>>4)&7, fq=(k>>3)&1, c=k&7, lane=fq*32+fm
//   addr = (((wv*(KDIM/128)+kh)*8 + t)*2 + hl)*512 + lane*8 + c   [ushorts]
// -> a wave's fragment load is base + lane*16B, perfectly coalesced.

// ---------------- merged prep + degree count (now also emits edge slot) -------
__global__ __launch_bounds__(256) void k_prep_deg(
    const float* __restrict__ wn, const float* __restrict__ w1,
    const float* __restrict__ bn, const float* __restrict__ w2,
    const float* __restrict__ b1, const float* __restrict__ b2,
    const int* __restrict__ dst,
    ushort_t* __restrict__ WcSw, float* __restrict__ bc,
    ushort_t* __restrict__ W2Sw, float* __restrict__ b1f,
    float* __restrict__ b2f, int* __restrict__ deg,
    int* __restrict__ epos) {
  int bid = blockIdx.x;
  if (bid < 128) {
    int j = bid;
    int k = threadIdx.x;
    float acc = 0.f;
    for (int m = 0; m < 128; m++)
      acc += w1[j * 128 + m] * wn[m * 256 + k];
    ushort_t h = f2bf(acc);
    ushort_t l = f2bf(acc - bf2f(h));
    int wv = j >> 5, fm = j & 31;
    int kh = k >> 7, t = (k >> 4) & 7, fq = (k >> 3) & 1, c = k & 7;
    int lane = fq * 32 + fm;
    int base = ((wv * 2 + kh) * 8 + t) * 2 * 512 + lane * 8 + c;  // KH=2
    WcSw[base] = h;
    WcSw[base + 512] = l;
    if (k == 0) {
      float s = 0.f;
      for (int m = 0; m < 128; m++) s += w1[j * 128 + m] * bn[m];
      bc[j] = s;
    }
  } else if (bid < 193) {
    int i = (bid - 128) * 256 + threadIdx.x;
    if (i >= 16640) return;
    if (i < 16384) {
      float v = w2[i];
      ushort_t h = f2bf(v);
      ushort_t l = f2bf(v - bf2f(h));
      int j = i >> 7, k = i & 127;
      int wv = j >> 5, fm = j & 31;
      int t = (k >> 4) & 7, fq = (k >> 3) & 1, c = k & 7;
      int lane = fq * 32 + fm;
      int base = (wv * 8 + t) * 2 * 512 + lane * 8 + c;  // KH=1
      W2Sw[base] = h;
      W2Sw[base + 512] = l;
    } else if (i < 16512) {
      b1f[i - 16384] = b1[i - 16384];
    } else {
      b2f[i - 16512] = b2[i - 16512];
    }
  } else {
    int e = (bid - 193) * 256 + threadIdx.x;
    // deg count AND per-edge slot in one atomic: the returned old value IS
    // this edge's position within dst's CSR row -> fill pass needs no atomic.
    if (e < N_EDGES) epos[e] = atomicAdd(&deg[dst[e]], 1);
  }
}

// ---------------- CSR scan ----------------

__global__ void k_partial(const int* __restrict__ deg, int* __restrict__ partial) {
  __shared__ int lds[256];
  int b = blockIdx.x, t = threadIdx.x;
  int base = b * SCAN_CHUNK + t * 4;
  int s = 0;
#pragma unroll
  for (int i = 0; i < 4; i++) {
    int idx = base + i;
    if (idx < N_NODES) s += deg[idx];
  }
  lds[t] = s;
  __syncthreads();
  for (int off = 128; off > 0; off >>= 1) {
    if (t < off) lds[t] += lds[t + off];
    __syncthreads();
  }
  if (t == 0) partial[b] = lds[0];
}

__global__ void k_scan_final(const int* __restrict__ deg, const int* __restrict__ partial,
                             int* __restrict__ row_start, float* __restrict__ dinv) {
  __shared__ int lds[256];
  __shared__ int plds[64];
  int b = blockIdx.x, t = threadIdx.x;
  if (t < N_CHUNKS) plds[t] = partial[t];
  __syncthreads();
  if (t == 0) {
    int s = 0;
    for (int i = 0; i < b; i++) s += plds[i];
    plds[63] = s;  // prefix of partials before this block (N_CHUNKS=49 < 63)
  }
  int base = b * SCAN_CHUNK + t * 4;
  int v[4];
  int s = 0;
#pragma unroll
  for (int i = 0; i < 4; i++) {
    int idx = base + i;
    v[i] = (idx < N_NODES) ? deg[idx] : 0;
    s += v[i];
  }
  lds[t] = s;
  __syncthreads();
  for (int off = 1; off < 256; off <<= 1) {
    int add = (t >= off) ? lds[t - off] : 0;
    __syncthreads();
    lds[t] += add;
    __syncthreads();
  }
  int excl = lds[t] - s + plds[63];
#pragma unroll
  for (int i = 0; i < 4; i++) {
    int idx = base + i;
    if (idx < N_NODES) {
      row_start[idx] = excl;
      dinv[idx] = rsqrtf((float)(v[i] + 1));  // +1 self-loop
      excl += v[i];
    }
  }
  if (b == 0 && t == 0) row_start[N_NODES] = N_EDGES;
}

// ---------------- MERGED conv1-GEMM + CSR-fill (fill is now atomic-free) -----
__global__ __launch_bounds__(256) void k_gemm_fill(
    const float* __restrict__ Xv, const int* __restrict__ tokens,
    const ushort_t* __restrict__ Wsw,
    const float* __restrict__ bias, const float* __restrict__ dinvp,
    ushort_t* __restrict__ OutT,
    const int* __restrict__ src, const int* __restrict__ dst,
    const int* __restrict__ row_start, const int* __restrict__ epos,
    int* __restrict__ csr) {
  constexpr int KDIM = D_IN;
  constexpr int KH = KDIM / 128;
  constexpr int XS = KDIM + 8;
  __shared__ __align__(16) ushort_t xh_lds[32 * XS];
  __shared__ __align__(16) ushort_t xl_lds[32 * XS];

  int bid = blockIdx.x;
  if (bid >= GEMM_BLOCKS) {
    // ---- CSR fill path: pure loads + one scatter store, no atomics ----
    int e = (bid - GEMM_BLOCKS) * 256 + threadIdx.x;
    if (e < N_EDGES) {
      int d = dst[e];
      csr[row_start[d] + epos[e]] = src[e];
    }
    return;
  }

  // ---- GEMM path ----
  int tid = threadIdx.x;
  int lane = tid & 63;
  int wv = tid >> 6;
  int node0 = bid * 32;
  int fm = lane & 31;
  int fq = lane >> 5;

  {
    constexpr int NT = (32 * KDIM / 4) / 256;  // 8
    float4 v[NT];
    int rows[NT], cs[NT];
#pragma unroll
    for (int i = 0; i < NT; i++) {
      int seg = tid + 256 * i;
      rows[i] = seg / (KDIM / 4);
      cs[i] = seg % (KDIM / 4);
      int tk = tokens[min(node0 + rows[i], N_NODES - 1)];
      v[i] = *(const float4*)&Xv[(size_t)tk * KDIM + 4 * cs[i]];
    }
#pragma unroll
    for (int i = 0; i < NT; i++) {
      ushort4 h, l;
      h.x = f2bf(v[i].x); l.x = f2bf(v[i].x - bf2f(h.x));
      h.y = f2bf(v[i].y); l.y = f2bf(v[i].y - bf2f(h.y));
      h.z = f2bf(v[i].z); l.z = f2bf(v[i].z - bf2f(h.z));
      h.w = f2bf(v[i].w); l.w = f2bf(v[i].w - bf2f(h.w));
      *(ushort4*)&xh_lds[rows[i] * XS + 4 * cs[i]] = h;
      *(ushort4*)&xl_lds[rows[i] * XS + 4 * cs[i]] = l;
    }
  }
  __syncthreads();

  f32x16 acc;
#pragma unroll
  for (int r = 0; r < 16; r++) acc[r] = 0.f;

#pragma unroll
  for (int kh = 0; kh < KH; kh++) {
    const ushort_t* wb = Wsw + ((size_t)(wv * KH + kh) * 8) * 2 * 512 + lane * 8;
    bf16x8 wbh[8], wbl[8];
#pragma unroll
    for (int t = 0; t < 8; t++) {
      wbh[t] = *(const bf16x8*)(wb + (size_t)t * 1024);
      wbl[t] = *(const bf16x8*)(wb + (size_t)t * 1024 + 512);
    }
#pragma unroll
    for (int t = 0; t < 8; t++) {
      int ko = kh * 128 + t * 16 + fq * 8;
      bf16x8 ah = *(const bf16x8*)&xh_lds[fm * XS + ko];
      bf16x8 al = *(const bf16x8*)&xl_lds[fm * XS + ko];
      acc = __builtin_amdgcn_mfma_f32_32x32x16_bf16(ah, wbh[t], acc, 0, 0, 0);
      acc = __builtin_amdgcn_mfma_f32_32x32x16_bf16(ah, wbl[t], acc, 0, 0, 0);
      acc = __builtin_amdgcn_mfma_f32_32x32x16_bf16(al, wbh[t], acc, 0, 0, 0);
    }
  }
  int j = wv * 32 + fm;
  float bv = bias[j];
#pragma unroll
  for (int r = 0; r < 16; r++) {
    int row = (r & 3) + 8 * (r >> 2) + 4 * fq;
    int node = node0 + row;
    if (node < N_NODES)
      OutT[(size_t)node * D + j] = f2bf((acc[r] + bv) * dinvp[node]);
  }
}

// ---------------- vectorized edge gather ----------------
// Lane decomposition: g = lane>>4 (edge subgroup, 4 edges in parallel),
// h = lane&15 (16B dim-chunk: dims h*8..h*8+7). One wave-load = 4 rows x 256B.
// 8 outstanding dwordx4 loads = 8KB in flight per wave (4x the scalar version).
__device__ __forceinline__ void addu4(float acc[8], uint4 u) {
  acc[0] += bf2f((ushort_t)(u.x & 0xFFFFu));
  acc[1] += bf2f((ushort_t)(u.x >> 16));
  acc[2] += bf2f((ushort_t)(u.y & 0xFFFFu));
  acc[3] += bf2f((ushort_t)(u.y >> 16));
  acc[4] += bf2f((ushort_t)(u.z & 0xFFFFu));
  acc[5] += bf2f((ushort_t)(u.z >> 16));
  acc[6] += bf2f((ushort_t)(u.w & 0xFFFFu));
  acc[7] += bf2f((ushort_t)(u.w >> 16));
}

__device__ __forceinline__ void agg_edges4(
    const uint4* __restrict__ tu4, const int* __restrict__ csr,
    int e0, int e1, int lane, int g, int h, float acc[8]) {
  for (int base = e0; base < e1; base += 64) {
    int cnt = min(64, e1 - base);
    int sidx = (lane < cnt) ? csr[base + lane] : 0;
    int i = 0;
    for (; i + 32 <= cnt; i += 32) {   // 8 loads (32 edges) in flight
      uint4 u[8];
#pragma unroll
      for (int q = 0; q < 8; q++) {
        int s = __shfl(sidx, i + 4 * q + g);
        u[q] = tu4[(size_t)s * 16 + h];
      }
#pragma unroll
      for (int q = 0; q < 8; q++) addu4(acc, u[q]);
    }
    for (; i + 8 <= cnt; i += 8) {     // 2 loads (8 edges) in flight
      uint4 u[2];
#pragma unroll
      for (int q = 0; q < 2; q++) {
        int s = __shfl(sidx, i + 4 * q + g);
        u[q] = tu4[(size_t)s * 16 + h];
      }
      addu4(acc, u[0]);
      addu4(acc, u[1]);
    }
    for (; i + 4 <= cnt; i += 4) {
      int s = __shfl(sidx, i + g);
      uint4 u = tu4[(size_t)s * 16 + h];
      addu4(acc, u);
    }
    if (i < cnt) {                     // 1..3 edge tail, predicated
      int r = cnt - i;
      int s = __shfl(sidx, (g < r) ? (i + g) : i);
      uint4 u = tu4[(size_t)s * 16 + h];
      if (g < r) addu4(acc, u);
    }
  }
}

// ---------------- FUSED aggregate1 + conv2-GEMM ----------------
__global__ __launch_bounds__(256) void k_agg_gemm(
    const ushort_t* __restrict__ t1, const int* __restrict__ row_start,
    const int* __restrict__ csr, const float* __restrict__ dinv,
    const float* __restrict__ b1f,
    const ushort_t* __restrict__ Wsw, ushort_t* __restrict__ OutT2) {
  constexpr int XS = 136;
  __shared__ __align__(16) ushort_t xh_lds[32 * XS];
  __shared__ __align__(16) ushort_t xl_lds[32 * XS];

  int tid = threadIdx.x;
  int lane = tid & 63;
  int wv = tid >> 6;
  int node0 = blockIdx.x * 32;
  int fm = lane & 31;
  int fq = lane >> 5;
  int g = lane >> 4;
  int h = lane & 15;

  const uint4* tu4 = (const uint4*)t1;
  float4 bA = *(const float4*)&b1f[h * 8];
  float4 bB = *(const float4*)&b1f[h * 8 + 4];

  for (int rr = 0; rr < 8; rr++) {
    int row = wv * 8 + rr;
    int node = node0 + row;
    float acc[8];
#pragma unroll
    for (int q = 0; q < 8; q++) acc[q] = 0.f;
    if (node < N_NODES)
      agg_edges4(tu4, csr, row_start[node], row_start[node + 1], lane, g, h, acc);
    // cross-group reduce: lanes {h, h+16, h+32, h+48} hold partial sums
#pragma unroll
    for (int q = 0; q < 8; q++) {
      acc[q] += __shfl_xor(acc[q], 16);
      acc[q] += __shfl_xor(acc[q], 32);
    }
    float v[8];
    if (node < N_NODES) {
      addu4(acc, tu4[(size_t)node * 16 + h]);  // self-loop (prescaled)
      float di = dinv[node];
      v[0] = fmaxf(di * acc[0] + bA.x, 0.f);
      v[1] = fmaxf(di * acc[1] + bA.y, 0.f);
      v[2] = fmaxf(di * acc[2] + bA.z, 0.f);
      v[3] = fmaxf(di * acc[3] + bA.w, 0.f);
      v[4] = fmaxf(di * acc[4] + bB.x, 0.f);
      v[5] = fmaxf(di * acc[5] + bB.y, 0.f);
      v[6] = fmaxf(di * acc[6] + bB.z, 0.f);
      v[7] = fmaxf(di * acc[7] + bB.w, 0.f);
    } else {
#pragma unroll
      for (int q = 0; q < 8; q++) v[q] = 0.f;
    }
    // groups 0/1 write the hi/lo bf16 row slices (values replicated x4 groups)
    if (g < 2) {
      bf16x8 pack;
#pragma unroll
      for (int q = 0; q < 8; q++) {
        ushort_t hq = f2bf(v[q]);
        pack[q] = (short)((g == 0) ? hq : f2bf(v[q] - bf2f(hq)));
      }
      ushort_t* dstp = (g == 0) ? &xh_lds[row * XS + h * 8]
                                : &xl_lds[row * XS + h * 8];
      *(bf16x8*)dstp = pack;
    }
  }
  __syncthreads();

  f32x16 acc;
#pragma unroll
  for (int r = 0; r < 16; r++) acc[r] = 0.f;
  {
    const ushort_t* wb = Wsw + ((size_t)wv * 8) * 2 * 512 + lane * 8;
    bf16x8 wbh[8], wbl[8];
#pragma unroll
    for (int t = 0; t < 8; t++) {
      wbh[t] = *(const bf16x8*)(wb + (size_t)t * 1024);
      wbl[t] = *(const bf16x8*)(wb + (size_t)t * 1024 + 512);
    }
#pragma unroll
    for (int t = 0; t < 8; t++) {
      int ko = t * 16 + fq * 8;
      bf16x8 ah = *(const bf16x8*)&xh_lds[fm * XS + ko];
      bf16x8 al = *(const bf16x8*)&xl_lds[fm * XS + ko];
      acc = __builtin_amdgcn_mfma_f32_32x32x16_bf16(ah, wbh[t], acc, 0, 0, 0);
      acc = __builtin_amdgcn_mfma_f32_32x32x16_bf16(ah, wbl[t], acc, 0, 0, 0);
      acc = __builtin_amdgcn_mfma_f32_32x32x16_bf16(al, wbh[t], acc, 0, 0, 0);
    }
  }
  int j = wv * 32 + fm;
#pragma unroll
  for (int r = 0; r < 16; r++) {
    int row = (r & 3) + 8 * (r >> 2) + 4 * fq;
    int node = node0 + row;
    if (node < N_NODES)
      OutT2[(size_t)node * D + j] = f2bf(acc[r] * dinv[node]);
  }
}

// ---------------- final aggregation -> fp32 out ----------------
__global__ __launch_bounds__(256) void k_aggregate_out(
    const ushort_t* __restrict__ t, const int* __restrict__ row_start,
    const int* __restrict__ csr, const float* __restrict__ dinv,
    const float* __restrict__ bias, float* __restrict__ out_f) {
  int wave = threadIdx.x >> 6;
  int lane = threadIdx.x & 63;
  int node = blockIdx.x * 4 + wave;
  if (node >= N_NODES) return;
  int g = lane >> 4;
  int h = lane & 15;
  const uint4* tu4 = (const uint4*)t;
  float acc[8];
#pragma unroll
  for (int q = 0; q < 8; q++) acc[q] = 0.f;
  agg_edges4(tu4, csr, row_start[node], row_start[node + 1], lane, g, h, acc);
#pragma unroll
  for (int q = 0; q < 8; q++) {
    acc[q] += __shfl_xor(acc[q], 16);
    acc[q] += __shfl_xor(acc[q], 32);
  }
  addu4(acc, tu4[(size_t)node * 16 + h]);  // self-loop
  float di = dinv[node];
  float4 bA = *(const float4*)&bias[h * 8];
  float4 bB = *(const float4*)&bias[h * 8 + 4];
  if (g == 0) {
    float4 o;
    o.x = di * acc[0] + bA.x;
    o.y = di * acc[1] + bA.y;
    o.z = di * acc[2] + bA.z;
    o.w = di * acc[3] + bA.w;
    *(float4*)&out_f[(size_t)node * D + h * 8] = o;
  } else if (g == 1) {
    float4 o;
    o.x = di * acc[4] + bB.x;
    o.y = di * acc[5] + bB.y;
    o.z = di * acc[6] + bB.z;
    o.w = di * acc[7] + bB.w;
    *(float4*)&out_f[(size_t)node * D + h * 8 + 4] = o;
  }
}

extern "C" void kernel_launch(void* const* d_in, const int* in_sizes, int n_in,
                              void* d_out, int out_size, void* d_ws, size_t ws_size,
                              hipStream_t stream) {
  const int* tokens = (const int*)d_in[0];
  const int* edge = (const int*)d_in[1];  // [2][E]
  const float* embed = (const float*)d_in[2];
  const float* Wn = (const float*)d_in[3];
  const float* bn = (const float*)d_in[4];
  const float* w1 = (const float*)d_in[5];
  const float* b1 = (const float*)d_in[6];
  const float* w2 = (const float*)d_in[7];
  const float* b2 = (const float*)d_in[8];
  float* out = (float*)d_out;  // fp32 output

  const int* src = edge;
  const int* dst = edge + N_EDGES;

  char* ws = (char*)d_ws;
  ushort_t* T1 = (ushort_t*)ws;                    // 12,800,000 B
  ushort_t* T2 = (ushort_t*)(ws + 12800000);       // 12,800,000 B
  int* epos = (int*)(ws + 25600000);               // 2,400,000 B (edge slot)
  float* dinv = (float*)(ws + 38400000);           // 200,000 B
  int* row_start = (int*)(ws + 38600064);          // 200,004 B (pad)
  int* deg = (int*)(ws + 38800128);                // 200,000 B
  int* csr = (int*)(ws + 39200128);                // 2,400,000 B
  int* partial = (int*)(ws + 41600192);            // 196 B
  ushort_t* WcSw = (ushort_t*)(ws + 41600512);     // 131,072 B (swizzled hi/lo)
  ushort_t* W2Sw = (ushort_t*)(ws + 41731584);     // 65,536 B (swizzled hi/lo)
  float* bias_ws = (float*)(ws + 41797120);        // bc | b1 | b2 (1,536 B)
  float* bcf = bias_ws;
  float* b1f = bias_ws + 128;
  float* b2f = bias_ws + 256;

  // --- zero deg; prep + degree count (emits per-edge CSR slot) ---
  hipMemsetAsync(deg, 0, N_NODES * sizeof(int), stream);
  k_prep_deg<<<193 + EDGE_BLOCKS, 256, 0, stream>>>(
      Wn, w1, bn, w2, b1, b2, dst, WcSw, bcf, W2Sw, b1f, b2f, deg, epos);

  // --- CSR scan ---
  k_partial<<<N_CHUNKS, 256, 0, stream>>>(deg, partial);
  k_scan_final<<<N_CHUNKS, 256, 0, stream>>>(deg, partial, row_start, dinv);

  // --- merged: conv1 T1 = (gather(e)@Wc^T + bc)*dinv  ||  CSR fill (no atomics) ---
  k_gemm_fill<<<GEMM_BLOCKS + EDGE_BLOCKS, 256, 0, stream>>>(
      embed, tokens, WcSw, bcf, dinv, T1, src, dst, row_start, epos, csr);

  // --- fused: x1 = relu(agg(T1)+b1); T2 = (x1 @ w2^T)*dinv ---
  k_agg_gemm<<<GEMM_BLOCKS, 256, 0, stream>>>(
      T1, row_start, csr, dinv, b1f, W2Sw, T2);

  // --- final aggregate + b2 -> out (fp32) ---
  k_aggregate_out<<<(N_NODES + 3) / 4, 256, 0, stream>>>(
      T2, row_start, csr, dinv, b2f, out);
}

// Round 2
// 232.336 us; speedup vs baseline: 1.1127x; 1.1127x over previous
//
#include <hip/hip_runtime.h>
#include <hip/hip_bf16.h>

#define N_NODES 50000
#define N_EDGES 600000
#define D_IN 256
#define D 128

#define SCAN_CHUNK 1024
#define N_CHUNKS ((N_NODES + SCAN_CHUNK - 1) / SCAN_CHUNK)  // 49
#define GEMM_BLOCKS ((N_NODES + 31) / 32)                   // 1563
#define EDGE_BLOCKS ((N_EDGES + 255) / 256)                 // 2344

typedef unsigned short ushort_t;
typedef __attribute__((ext_vector_type(8))) short bf16x8;
typedef __attribute__((ext_vector_type(16))) float f32x16;

__device__ __forceinline__ float bf2f(ushort_t u) {
  union { unsigned int i; float f; } v;
  v.i = ((unsigned int)u) << 16;
  return v.f;
}
__device__ __forceinline__ ushort_t f2bf(float f) {
  union { float f; unsigned int i; } v;
  v.f = f;
  unsigned int x = v.i;
  unsigned int r = (x + 0x7FFFu + ((x >> 16) & 1u)) >> 16;  // RNE
  return (ushort_t)r;
}

// Swizzled-W addressing: element (j,k) of [128,KDIM] W, hi/lo split:
//   wv=j>>5, fm=j&31, kh=k>>7, t=(k>>4)&7, fq=(k>>3)&1, c=k&7, lane=fq*32+fm
//   addr = (((wv*(KDIM/128)+kh)*8 + t)*2 + hl)*512 + lane*8 + c   [ushorts]
// -> a wave's fragment load is base + lane*16B, perfectly coalesced.

// ---------------- merged prep + degree count (emits edge slot) ----------------
__global__ __launch_bounds__(256) void k_prep_deg(
    const float* __restrict__ wn, const float* __restrict__ w1,
    const float* __restrict__ bn, const float* __restrict__ w2,
    const float* __restrict__ b1, const float* __restrict__ b2,
    const int* __restrict__ dst,
    ushort_t* __restrict__ WcSw, float* __restrict__ bc,
    ushort_t* __restrict__ W2Sw, float* __restrict__ b1f,
    float* __restrict__ b2f, int* __restrict__ deg,
    int* __restrict__ epos) {
  int bid = blockIdx.x;
  if (bid < 128) {
    int j = bid;
    int k = threadIdx.x;
    float acc = 0.f;
    for (int m = 0; m < 128; m++)
      acc += w1[j * 128 + m] * wn[m * 256 + k];
    ushort_t h = f2bf(acc);
    ushort_t l = f2bf(acc - bf2f(h));
    int wv = j >> 5, fm = j & 31;
    int kh = k >> 7, t = (k >> 4) & 7, fq = (k >> 3) & 1, c = k & 7;
    int lane = fq * 32 + fm;
    int base = ((wv * 2 + kh) * 8 + t) * 2 * 512 + lane * 8 + c;  // KH=2
    WcSw[base] = h;
    WcSw[base + 512] = l;
    if (k == 0) {
      float s = 0.f;
      for (int m = 0; m < 128; m++) s += w1[j * 128 + m] * bn[m];
      bc[j] = s;
    }
  } else if (bid < 193) {
    int i = (bid - 128) * 256 + threadIdx.x;
    if (i >= 16640) return;
    if (i < 16384) {
      float v = w2[i];
      ushort_t h = f2bf(v);
      ushort_t l = f2bf(v - bf2f(h));
      int j = i >> 7, k = i & 127;
      int wv = j >> 5, fm = j & 31;
      int t = (k >> 4) & 7, fq = (k >> 3) & 1, c = k & 7;
      int lane = fq * 32 + fm;
      int base = (wv * 8 + t) * 2 * 512 + lane * 8 + c;  // KH=1
      W2Sw[base] = h;
      W2Sw[base + 512] = l;
    } else if (i < 16512) {
      b1f[i - 16384] = b1[i - 16384];
    } else {
      b2f[i - 16512] = b2[i - 16512];
    }
  } else {
    int e = (bid - 193) * 256 + threadIdx.x;
    // deg count AND per-edge slot in one atomic: returned old value IS this
    // edge's position within dst's CSR row -> fill pass needs no atomic.
    if (e < N_EDGES) epos[e] = atomicAdd(&deg[dst[e]], 1);
  }
}

// ---------------- CSR scan ----------------

__global__ void k_partial(const int* __restrict__ deg, int* __restrict__ partial) {
  __shared__ int lds[256];
  int b = blockIdx.x, t = threadIdx.x;
  int base = b * SCAN_CHUNK + t * 4;
  int s = 0;
#pragma unroll
  for (int i = 0; i < 4; i++) {
    int idx = base + i;
    if (idx < N_NODES) s += deg[idx];
  }
  lds[t] = s;
  __syncthreads();
  for (int off = 128; off > 0; off >>= 1) {
    if (t < off) lds[t] += lds[t + off];
    __syncthreads();
  }
  if (t == 0) partial[b] = lds[0];
}

__global__ void k_scan_final(const int* __restrict__ deg, const int* __restrict__ partial,
                             int* __restrict__ row_start, float* __restrict__ dinv) {
  __shared__ int lds[256];
  __shared__ int plds[64];
  int b = blockIdx.x, t = threadIdx.x;
  if (t < N_CHUNKS) plds[t] = partial[t];
  __syncthreads();
  if (t == 0) {
    int s = 0;
    for (int i = 0; i < b; i++) s += plds[i];
    plds[63] = s;  // prefix of partials before this block (N_CHUNKS=49 < 63)
  }
  int base = b * SCAN_CHUNK + t * 4;
  int v[4];
  int s = 0;
#pragma unroll
  for (int i = 0; i < 4; i++) {
    int idx = base + i;
    v[i] = (idx < N_NODES) ? deg[idx] : 0;
    s += v[i];
  }
  lds[t] = s;
  __syncthreads();
  for (int off = 1; off < 256; off <<= 1) {
    int add = (t >= off) ? lds[t - off] : 0;
    __syncthreads();
    lds[t] += add;
    __syncthreads();
  }
  int excl = lds[t] - s + plds[63];
#pragma unroll
  for (int i = 0; i < 4; i++) {
    int idx = base + i;
    if (idx < N_NODES) {
      row_start[idx] = excl;
      dinv[idx] = rsqrtf((float)(v[i] + 1));  // +1 self-loop
      excl += v[i];
    }
  }
  if (b == 0 && t == 0) row_start[N_NODES] = N_EDGES;
}

// ---------------- MERGED conv1-GEMM + CSR-fill (fill is atomic-free) ---------
__global__ __launch_bounds__(256) void k_gemm_fill(
    const float* __restrict__ Xv, const int* __restrict__ tokens,
    const ushort_t* __restrict__ Wsw,
    const float* __restrict__ bias, const float* __restrict__ dinvp,
    ushort_t* __restrict__ OutT,
    const int* __restrict__ src, const int* __restrict__ dst,
    const int* __restrict__ row_start, const int* __restrict__ epos,
    int* __restrict__ csr) {
  constexpr int KDIM = D_IN;
  constexpr int KH = KDIM / 128;
  constexpr int XS = KDIM + 8;
  __shared__ __align__(16) ushort_t xh_lds[32 * XS];
  __shared__ __align__(16) ushort_t xl_lds[32 * XS];

  int bid = blockIdx.x;
  if (bid >= GEMM_BLOCKS) {
    // ---- CSR fill path: pure loads + one scatter store, no atomics ----
    int e = (bid - GEMM_BLOCKS) * 256 + threadIdx.x;
    if (e < N_EDGES) {
      int d = dst[e];
      csr[row_start[d] + epos[e]] = src[e];
    }
    return;
  }

  // ---- GEMM path ----
  int tid = threadIdx.x;
  int lane = tid & 63;
  int wv = tid >> 6;
  int node0 = bid * 32;
  int fm = lane & 31;
  int fq = lane >> 5;

  {
    constexpr int NT = (32 * KDIM / 4) / 256;  // 8
    float4 v[NT];
    int rows[NT], cs[NT];
#pragma unroll
    for (int i = 0; i < NT; i++) {
      int seg = tid + 256 * i;
      rows[i] = seg / (KDIM / 4);
      cs[i] = seg % (KDIM / 4);
      int tk = tokens[min(node0 + rows[i], N_NODES - 1)];
      v[i] = *(const float4*)&Xv[(size_t)tk * KDIM + 4 * cs[i]];
    }
#pragma unroll
    for (int i = 0; i < NT; i++) {
      ushort4 h, l;
      h.x = f2bf(v[i].x); l.x = f2bf(v[i].x - bf2f(h.x));
      h.y = f2bf(v[i].y); l.y = f2bf(v[i].y - bf2f(h.y));
      h.z = f2bf(v[i].z); l.z = f2bf(v[i].z - bf2f(h.z));
      h.w = f2bf(v[i].w); l.w = f2bf(v[i].w - bf2f(h.w));
      *(ushort4*)&xh_lds[rows[i] * XS + 4 * cs[i]] = h;
      *(ushort4*)&xl_lds[rows[i] * XS + 4 * cs[i]] = l;
    }
  }
  __syncthreads();

  f32x16 acc;
#pragma unroll
  for (int r = 0; r < 16; r++) acc[r] = 0.f;

#pragma unroll
  for (int kh = 0; kh < KH; kh++) {
    const ushort_t* wb = Wsw + ((size_t)(wv * KH + kh) * 8) * 2 * 512 + lane * 8;
    bf16x8 wbh[8], wbl[8];
#pragma unroll
    for (int t = 0; t < 8; t++) {
      wbh[t] = *(const bf16x8*)(wb + (size_t)t * 1024);
      wbl[t] = *(const bf16x8*)(wb + (size_t)t * 1024 + 512);
    }
#pragma unroll
    for (int t = 0; t < 8; t++) {
      int ko = kh * 128 + t * 16 + fq * 8;
      bf16x8 ah = *(const bf16x8*)&xh_lds[fm * XS + ko];
      bf16x8 al = *(const bf16x8*)&xl_lds[fm * XS + ko];
      acc = __builtin_amdgcn_mfma_f32_32x32x16_bf16(ah, wbh[t], acc, 0, 0, 0);
      acc = __builtin_amdgcn_mfma_f32_32x32x16_bf16(ah, wbl[t], acc, 0, 0, 0);
      acc = __builtin_amdgcn_mfma_f32_32x32x16_bf16(al, wbh[t], acc, 0, 0, 0);
    }
  }
  int j = wv * 32 + fm;
  float bv = bias[j];
#pragma unroll
  for (int r = 0; r < 16; r++) {
    int row = (r & 3) + 8 * (r >> 2) + 4 * fq;
    int node = node0 + row;
    if (node < N_NODES)
      OutT[(size_t)node * D + j] = f2bf((acc[r] + bv) * dinvp[node]);
  }
}

// ---------------- group-parallel edge gather ----------------
// 16 lanes = 1 node; lane h = lane&15 owns dims h*8..h*8+7 (one uint4 = 16B).
// One load instruction fetches a FULL 256B row per group; 4 independent node
// chains per wave; 8-deep batches = 32 rows (8KB) in flight per wave.
// No cross-lane reduction needed: each (group, h) owns distinct dims.
__device__ __forceinline__ void addu4(float acc[8], uint4 u) {
  acc[0] += bf2f((ushort_t)(u.x & 0xFFFFu));
  acc[1] += bf2f((ushort_t)(u.x >> 16));
  acc[2] += bf2f((ushort_t)(u.y & 0xFFFFu));
  acc[3] += bf2f((ushort_t)(u.y >> 16));
  acc[4] += bf2f((ushort_t)(u.z & 0xFFFFu));
  acc[5] += bf2f((ushort_t)(u.z >> 16));
  acc[6] += bf2f((ushort_t)(u.w & 0xFFFFu));
  acc[7] += bf2f((ushort_t)(u.w >> 16));
}

__device__ __forceinline__ void agg_group(
    const uint4* __restrict__ tu4, const int* __restrict__ csr,
    int e0, int e1, int lane, int h, float acc[8]) {
  int gbase = lane & 48;  // group's first lane (for group-relative shfl)
  for (int base = e0; base < e1; base += 16) {
    int cnt = min(16, e1 - base);
    int sidx = (h < cnt) ? csr[base + h] : 0;  // one csr RT per batch per group
    int i = 0;
    for (; i + 8 <= cnt; i += 8) {  // 8 rows in flight per group
      uint4 u[8];
#pragma unroll
      for (int q = 0; q < 8; q++) {
        int s = __shfl(sidx, gbase + i + q);
        u[q] = tu4[(size_t)s * 16 + h];
      }
#pragma unroll
      for (int q = 0; q < 8; q++) addu4(acc, u[q]);
    }
    if (i + 4 <= cnt) {
      uint4 u[4];
#pragma unroll
      for (int q = 0; q < 4; q++) {
        int s = __shfl(sidx, gbase + i + q);
        u[q] = tu4[(size_t)s * 16 + h];
      }
#pragma unroll
      for (int q = 0; q < 4; q++) addu4(acc, u[q]);
      i += 4;
    }
    if (i + 2 <= cnt) {
      uint4 u[2];
#pragma unroll
      for (int q = 0; q < 2; q++) {
        int s = __shfl(sidx, gbase + i + q);
        u[q] = tu4[(size_t)s * 16 + h];
      }
      addu4(acc, u[0]);
      addu4(acc, u[1]);
      i += 2;
    }
    if (i < cnt) {
      int s = __shfl(sidx, gbase + i);
      uint4 u = tu4[(size_t)s * 16 + h];
      addu4(acc, u);
    }
  }
}

// ---------------- FUSED aggregate1 + conv2-GEMM ----------------
__global__ __launch_bounds__(256) void k_agg_gemm(
    const ushort_t* __restrict__ t1, const int* __restrict__ row_start,
    const int* __restrict__ csr, const float* __restrict__ dinv,
    const float* __restrict__ b1f,
    const ushort_t* __restrict__ Wsw, ushort_t* __restrict__ OutT2) {
  constexpr int XS = 136;
  __shared__ __align__(16) ushort_t xh_lds[32 * XS];
  __shared__ __align__(16) ushort_t xl_lds[32 * XS];

  int tid = threadIdx.x;
  int lane = tid & 63;
  int wv = tid >> 6;
  int node0 = blockIdx.x * 32;
  int fm = lane & 31;
  int fq = lane >> 5;
  int g = lane >> 4;   // group 0..3 (node within pass)
  int h = lane & 15;   // dim-chunk 0..15

  const uint4* tu4 = (const uint4*)t1;
  float4 bA = *(const float4*)&b1f[h * 8];
  float4 bB = *(const float4*)&b1f[h * 8 + 4];

  // hoist row boundaries for this wave's 8 nodes: lanes 0..8 load them
  int node0w = node0 + wv * 8;
  int rsv = row_start[min(node0w + min(lane, 8), N_NODES)];

#pragma unroll
  for (int p = 0; p < 2; p++) {
    int r = p * 4 + g;           // wave-local row 0..7
    int row = wv * 8 + r;
    int node = node0 + row;
    int e0 = __shfl(rsv, r);
    int e1 = __shfl(rsv, r + 1);
    float acc[8];
#pragma unroll
    for (int q = 0; q < 8; q++) acc[q] = 0.f;
    if (node < N_NODES) {
      agg_group(tu4, csr, e0, e1, lane, h, acc);
      addu4(acc, tu4[(size_t)node * 16 + h]);  // self-loop (prescaled)
    }
    bf16x8 ph, pl;
    if (node < N_NODES) {
      float di = dinv[node];
      float v[8];
      v[0] = fmaxf(di * acc[0] + bA.x, 0.f);
      v[1] = fmaxf(di * acc[1] + bA.y, 0.f);
      v[2] = fmaxf(di * acc[2] + bA.z, 0.f);
      v[3] = fmaxf(di * acc[3] + bA.w, 0.f);
      v[4] = fmaxf(di * acc[4] + bB.x, 0.f);
      v[5] = fmaxf(di * acc[5] + bB.y, 0.f);
      v[6] = fmaxf(di * acc[6] + bB.z, 0.f);
      v[7] = fmaxf(di * acc[7] + bB.w, 0.f);
#pragma unroll
      for (int q = 0; q < 8; q++) {
        ushort_t hq = f2bf(v[q]);
        ph[q] = (short)hq;
        pl[q] = (short)f2bf(v[q] - bf2f(hq));
      }
    } else {
#pragma unroll
      for (int q = 0; q < 8; q++) { ph[q] = 0; pl[q] = 0; }
    }
    *(bf16x8*)&xh_lds[row * XS + h * 8] = ph;
    *(bf16x8*)&xl_lds[row * XS + h * 8] = pl;
  }
  __syncthreads();

  f32x16 acc;
#pragma unroll
  for (int r = 0; r < 16; r++) acc[r] = 0.f;
  {
    const ushort_t* wb = Wsw + ((size_t)wv * 8) * 2 * 512 + lane * 8;
    bf16x8 wbh[8], wbl[8];
#pragma unroll
    for (int t = 0; t < 8; t++) {
      wbh[t] = *(const bf16x8*)(wb + (size_t)t * 1024);
      wbl[t] = *(const bf16x8*)(wb + (size_t)t * 1024 + 512);
    }
#pragma unroll
    for (int t = 0; t < 8; t++) {
      int ko = t * 16 + fq * 8;
      bf16x8 ah = *(const bf16x8*)&xh_lds[fm * XS + ko];
      bf16x8 al = *(const bf16x8*)&xl_lds[fm * XS + ko];
      acc = __builtin_amdgcn_mfma_f32_32x32x16_bf16(ah, wbh[t], acc, 0, 0, 0);
      acc = __builtin_amdgcn_mfma_f32_32x32x16_bf16(ah, wbl[t], acc, 0, 0, 0);
      acc = __builtin_amdgcn_mfma_f32_32x32x16_bf16(al, wbh[t], acc, 0, 0, 0);
    }
  }
  int j = wv * 32 + fm;
#pragma unroll
  for (int r = 0; r < 16; r++) {
    int row = (r & 3) + 8 * (r >> 2) + 4 * fq;
    int node = node0 + row;
    if (node < N_NODES)
      OutT2[(size_t)node * D + j] = f2bf(acc[r] * dinv[node]);
  }
}

// ---------------- final aggregation -> fp32 out ----------------
// 4 nodes per wave (16 lanes each), 16 nodes per block.
__global__ __launch_bounds__(256) void k_aggregate_out(
    const ushort_t* __restrict__ t, const int* __restrict__ row_start,
    const int* __restrict__ csr, const float* __restrict__ dinv,
    const float* __restrict__ bias, float* __restrict__ out_f) {
  int wv = threadIdx.x >> 6;
  int lane = threadIdx.x & 63;
  int g = lane >> 4;
  int h = lane & 15;
  int nodew = blockIdx.x * 16 + wv * 4;
  int rsv = row_start[min(nodew + min(lane, 4), N_NODES)];
  int node = nodew + g;
  int e0 = __shfl(rsv, g);
  int e1 = __shfl(rsv, g + 1);
  if (node >= N_NODES) return;

  const uint4* tu4 = (const uint4*)t;
  float acc[8];
#pragma unroll
  for (int q = 0; q < 8; q++) acc[q] = 0.f;
  agg_group(tu4, csr, e0, e1, lane, h, acc);
  addu4(acc, tu4[(size_t)node * 16 + h]);  // self-loop
  float di = dinv[node];
  float4 bA = *(const float4*)&bias[h * 8];
  float4 bB = *(const float4*)&bias[h * 8 + 4];
  float4 o0, o1;
  o0.x = di * acc[0] + bA.x;
  o0.y = di * acc[1] + bA.y;
  o0.z = di * acc[2] + bA.z;
  o0.w = di * acc[3] + bA.w;
  o1.x = di * acc[4] + bB.x;
  o1.y = di * acc[5] + bB.y;
  o1.z = di * acc[6] + bB.z;
  o1.w = di * acc[7] + bB.w;
  *(float4*)&out_f[(size_t)node * D + h * 8] = o0;
  *(float4*)&out_f[(size_t)node * D + h * 8 + 4] = o1;
}

extern "C" void kernel_launch(void* const* d_in, const int* in_sizes, int n_in,
                              void* d_out, int out_size, void* d_ws, size_t ws_size,
                              hipStream_t stream) {
  const int* tokens = (const int*)d_in[0];
  const int* edge = (const int*)d_in[1];  // [2][E]
  const float* embed = (const float*)d_in[2];
  const float* Wn = (const float*)d_in[3];
  const float* bn = (const float*)d_in[4];
  const float* w1 = (const float*)d_in[5];
  const float* b1 = (const float*)d_in[6];
  const float* w2 = (const float*)d_in[7];
  const float* b2 = (const float*)d_in[8];
  float* out = (float*)d_out;  // fp32 output

  const int* src = edge;
  const int* dst = edge + N_EDGES;

  char* ws = (char*)d_ws;
  ushort_t* T1 = (ushort_t*)ws;                    // 12,800,000 B
  ushort_t* T2 = (ushort_t*)(ws + 12800000);       // 12,800,000 B
  int* epos = (int*)(ws + 25600000);               // 2,400,000 B (edge slot)
  float* dinv = (float*)(ws + 38400000);           // 200,000 B
  int* row_start = (int*)(ws + 38600064);          // 200,004 B (pad)
  int* deg = (int*)(ws + 38800128);                // 200,000 B
  int* csr = (int*)(ws + 39200128);                // 2,400,000 B
  int* partial = (int*)(ws + 41600192);            // 196 B
  ushort_t* WcSw = (ushort_t*)(ws + 41600512);     // 131,072 B (swizzled hi/lo)
  ushort_t* W2Sw = (ushort_t*)(ws + 41731584);     // 65,536 B (swizzled hi/lo)
  float* bias_ws = (float*)(ws + 41797120);        // bc | b1 | b2 (1,536 B)
  float* bcf = bias_ws;
  float* b1f = bias_ws + 128;
  float* b2f = bias_ws + 256;

  // --- zero deg; prep + degree count (emits per-edge CSR slot) ---
  hipMemsetAsync(deg, 0, N_NODES * sizeof(int), stream);
  k_prep_deg<<<193 + EDGE_BLOCKS, 256, 0, stream>>>(
      Wn, w1, bn, w2, b1, b2, dst, WcSw, bcf, W2Sw, b1f, b2f, deg, epos);

  // --- CSR scan ---
  k_partial<<<N_CHUNKS, 256, 0, stream>>>(deg, partial);
  k_scan_final<<<N_CHUNKS, 256, 0, stream>>>(deg, partial, row_start, dinv);

  // --- merged: conv1 T1 = (gather(e)@Wc^T + bc)*dinv  ||  CSR fill (no atomics) ---
  k_gemm_fill<<<GEMM_BLOCKS + EDGE_BLOCKS, 256, 0, stream>>>(
      embed, tokens, WcSw, bcf, dinv, T1, src, dst, row_start, epos, csr);

  // --- fused: x1 = relu(agg(T1)+b1); T2 = (x1 @ w2^T)*dinv ---
  k_agg_gemm<<<GEMM_BLOCKS, 256, 0, stream>>>(
      T1, row_start, csr, dinv, b1f, W2Sw, T2);

  // --- final aggregate + b2 -> out (fp32) ---
  k_aggregate_out<<<(N_NODES + 15) / 16, 256, 0, stream>>>(
      T2, row_start, csr, dinv, b2f, out);
}

// Round 3
// 231.351 us; speedup vs baseline: 1.1174x; 1.0043x over previous
//
#include <hip/hip_runtime.h>
#include <hip/hip_bf16.h>

#define N_NODES 50000
#define N_EDGES 600000
#define D_IN 256
#define D 128

#define SCAN_CHUNK 1024
#define N_CHUNKS ((N_NODES + SCAN_CHUNK - 1) / SCAN_CHUNK)  // 49
#define GEMM_BLOCKS ((N_NODES + 31) / 32)                   // 1563
#define EDGE_BLOCKS ((N_EDGES + 255) / 256)                 // 2344

typedef unsigned short ushort_t;
typedef __attribute__((ext_vector_type(8))) short bf16x8;
typedef __attribute__((ext_vector_type(16))) float f32x16;

__device__ __forceinline__ float bf2f(ushort_t u) {
  union { unsigned int i; float f; } v;
  v.i = ((unsigned int)u) << 16;
  return v.f;
}
__device__ __forceinline__ ushort_t f2bf(float f) {
  union { float f; unsigned int i; } v;
  v.f = f;
  unsigned int x = v.i;
  unsigned int r = (x + 0x7FFFu + ((x >> 16) & 1u)) >> 16;  // RNE
  return (ushort_t)r;
}
// cheap packed-bf16 extraction: 1 VALU each
__device__ __forceinline__ float bflo(unsigned int u) {
  union { unsigned int i; float f; } v;
  v.i = u << 16;
  return v.f;
}
__device__ __forceinline__ float bfhi(unsigned int u) {
  union { unsigned int i; float f; } v;
  v.i = u & 0xFFFF0000u;
  return v.f;
}

// Swizzled-W addressing: element (j,k) of [128,KDIM] W, hi/lo split:
//   wv=j>>5, fm=j&31, kh=k>>7, t=(k>>4)&7, fq=(k>>3)&1, c=k&7, lane=fq*32+fm
//   addr = (((wv*(KDIM/128)+kh)*8 + t)*2 + hl)*512 + lane*8 + c   [ushorts]

// ---------------- merged prep + degree count (emits edge slot) ----------------
__global__ __launch_bounds__(256) void k_prep_deg(
    const float* __restrict__ wn, const float* __restrict__ w1,
    const float* __restrict__ bn, const float* __restrict__ w2,
    const float* __restrict__ b1, const float* __restrict__ b2,
    const int* __restrict__ dst,
    ushort_t* __restrict__ WcSw, float* __restrict__ bc,
    ushort_t* __restrict__ W2Sw, float* __restrict__ b1f,
    float* __restrict__ b2f, int* __restrict__ deg,
    int* __restrict__ epos) {
  int bid = blockIdx.x;
  if (bid < 128) {
    int j = bid;
    int k = threadIdx.x;
    float acc = 0.f;
    for (int m = 0; m < 128; m++)
      acc += w1[j * 128 + m] * wn[m * 256 + k];
    ushort_t h = f2bf(acc);
    ushort_t l = f2bf(acc - bf2f(h));
    int wv = j >> 5, fm = j & 31;
    int kh = k >> 7, t = (k >> 4) & 7, fq = (k >> 3) & 1, c = k & 7;
    int lane = fq * 32 + fm;
    int base = ((wv * 2 + kh) * 8 + t) * 2 * 512 + lane * 8 + c;  // KH=2
    WcSw[base] = h;
    WcSw[base + 512] = l;
    if (k == 0) {
      float s = 0.f;
      for (int m = 0; m < 128; m++) s += w1[j * 128 + m] * bn[m];
      bc[j] = s;
    }
  } else if (bid < 193) {
    int i = (bid - 128) * 256 + threadIdx.x;
    if (i >= 16640) return;
    if (i < 16384) {
      float v = w2[i];
      ushort_t h = f2bf(v);
      ushort_t l = f2bf(v - bf2f(h));
      int j = i >> 7, k = i & 127;
      int wv = j >> 5, fm = j & 31;
      int t = (k >> 4) & 7, fq = (k >> 3) & 1, c = k & 7;
      int lane = fq * 32 + fm;
      int base = (wv * 8 + t) * 2 * 512 + lane * 8 + c;  // KH=1
      W2Sw[base] = h;
      W2Sw[base + 512] = l;
    } else if (i < 16512) {
      b1f[i - 16384] = b1[i - 16384];
    } else {
      b2f[i - 16512] = b2[i - 16512];
    }
  } else {
    int e = (bid - 193) * 256 + threadIdx.x;
    // deg count AND per-edge slot in one atomic: returned old value IS this
    // edge's position within dst's CSR row -> fill pass needs no atomic.
    if (e < N_EDGES) epos[e] = atomicAdd(&deg[dst[e]], 1);
  }
}

// ---------------- CSR scan ----------------

__global__ void k_partial(const int* __restrict__ deg, int* __restrict__ partial) {
  __shared__ int lds[256];
  int b = blockIdx.x, t = threadIdx.x;
  int base = b * SCAN_CHUNK + t * 4;
  int s = 0;
#pragma unroll
  for (int i = 0; i < 4; i++) {
    int idx = base + i;
    if (idx < N_NODES) s += deg[idx];
  }
  lds[t] = s;
  __syncthreads();
  for (int off = 128; off > 0; off >>= 1) {
    if (t < off) lds[t] += lds[t + off];
    __syncthreads();
  }
  if (t == 0) partial[b] = lds[0];
}

// Also zeroes the shared dummy row T1[N_NODES], T2[N_NODES] (gather padding).
__global__ void k_scan_final(const int* __restrict__ deg, const int* __restrict__ partial,
                             int* __restrict__ row_start, float* __restrict__ dinv,
                             ushort_t* __restrict__ T1z, ushort_t* __restrict__ T2z) {
  __shared__ int lds[256];
  __shared__ int plds[64];
  int b = blockIdx.x, t = threadIdx.x;
  if (t < N_CHUNKS) plds[t] = partial[t];
  __syncthreads();
  if (t == 0) {
    int s = 0;
    for (int i = 0; i < b; i++) s += plds[i];
    plds[63] = s;  // prefix of partials before this block (N_CHUNKS=49 < 63)
  }
  int base = b * SCAN_CHUNK + t * 4;
  int v[4];
  int s = 0;
#pragma unroll
  for (int i = 0; i < 4; i++) {
    int idx = base + i;
    v[i] = (idx < N_NODES) ? deg[idx] : 0;
    s += v[i];
  }
  lds[t] = s;
  __syncthreads();
  for (int off = 1; off < 256; off <<= 1) {
    int add = (t >= off) ? lds[t - off] : 0;
    __syncthreads();
    lds[t] += add;
    __syncthreads();
  }
  int excl = lds[t] - s + plds[63];
#pragma unroll
  for (int i = 0; i < 4; i++) {
    int idx = base + i;
    if (idx < N_NODES) {
      row_start[idx] = excl;
      dinv[idx] = rsqrtf((float)(v[i] + 1));  // +1 self-loop
      excl += v[i];
    }
  }
  if (b == 0) {
    if (t == 0) row_start[N_NODES] = N_EDGES;
    // zero dummy rows (128 bf16 = 64 uints each)
    unsigned int* z1 = (unsigned int*)&T1z[(size_t)N_NODES * D];
    unsigned int* z2 = (unsigned int*)&T2z[(size_t)N_NODES * D];
    if (t < 64) z1[t] = 0u;
    else if (t < 128) z2[t - 64] = 0u;
  }
}

// ---------------- MERGED conv1-GEMM + CSR-fill ----------------
// K-split staging: one 17.4KB LDS buffer reused for the two K=128 halves
// -> 8 blocks/CU (was 4 with the 33KB full-K buffer), for BOTH the GEMM
// blocks and the co-dispatched fill blocks.
__global__ __launch_bounds__(256) void k_gemm_fill(
    const float* __restrict__ Xv, const int* __restrict__ tokens,
    const ushort_t* __restrict__ Wsw,
    const float* __restrict__ bias, const float* __restrict__ dinvp,
    ushort_t* __restrict__ OutT,
    const int* __restrict__ src, const int* __restrict__ dst,
    const int* __restrict__ row_start, const int* __restrict__ epos,
    int* __restrict__ csr) {
  constexpr int XS = 136;
  __shared__ __align__(16) ushort_t xh_lds[32 * XS];
  __shared__ __align__(16) ushort_t xl_lds[32 * XS];

  int bid = blockIdx.x;
  if (bid >= GEMM_BLOCKS) {
    // ---- CSR fill path: pure loads + one scatter store, no atomics ----
    int e = (bid - GEMM_BLOCKS) * 256 + threadIdx.x;
    if (e < N_EDGES) {
      int d = dst[e];
      csr[row_start[d] + epos[e]] = src[e];
    }
    return;
  }

  // ---- GEMM path ----
  int tid = threadIdx.x;
  int lane = tid & 63;
  int wv = tid >> 6;
  int node0 = bid * 32;
  int fm = lane & 31;
  int fq = lane >> 5;
  int r8 = tid >> 5;   // 0..7
  int c32 = tid & 31;  // 0..31

  // load full rows (both K-halves) up-front: 8 independent float4 loads
  float4 v0[4], v1[4];
  int rows[4];
#pragma unroll
  for (int i = 0; i < 4; i++) {
    rows[i] = r8 * 4 + i;
    int tk = tokens[min(node0 + rows[i], N_NODES - 1)];
    const float* rp = &Xv[(size_t)tk * D_IN];
    v0[i] = *(const float4*)&rp[4 * c32];
    v1[i] = *(const float4*)&rp[128 + 4 * c32];
  }

  f32x16 acc;
#pragma unroll
  for (int r = 0; r < 16; r++) acc[r] = 0.f;

#pragma unroll
  for (int kh = 0; kh < 2; kh++) {
    // convert this half into the (reused) LDS buffer
#pragma unroll
    for (int i = 0; i < 4; i++) {
      float4 v = (kh == 0) ? v0[i] : v1[i];
      ushort4 h, l;
      h.x = f2bf(v.x); l.x = f2bf(v.x - bf2f(h.x));
      h.y = f2bf(v.y); l.y = f2bf(v.y - bf2f(h.y));
      h.z = f2bf(v.z); l.z = f2bf(v.z - bf2f(h.z));
      h.w = f2bf(v.w); l.w = f2bf(v.w - bf2f(h.w));
      *(ushort4*)&xh_lds[rows[i] * XS + 4 * c32] = h;
      *(ushort4*)&xl_lds[rows[i] * XS + 4 * c32] = l;
    }
    __syncthreads();

    const ushort_t* wb = Wsw + ((size_t)(wv * 2 + kh) * 8) * 2 * 512 + lane * 8;
    bf16x8 wbh[8], wbl[8];
#pragma unroll
    for (int t = 0; t < 8; t++) {
      wbh[t] = *(const bf16x8*)(wb + (size_t)t * 1024);
      wbl[t] = *(const bf16x8*)(wb + (size_t)t * 1024 + 512);
    }
#pragma unroll
    for (int t = 0; t < 8; t++) {
      int ko = t * 16 + fq * 8;
      bf16x8 ah = *(const bf16x8*)&xh_lds[fm * XS + ko];
      bf16x8 al = *(const bf16x8*)&xl_lds[fm * XS + ko];
      acc = __builtin_amdgcn_mfma_f32_32x32x16_bf16(ah, wbh[t], acc, 0, 0, 0);
      acc = __builtin_amdgcn_mfma_f32_32x32x16_bf16(ah, wbl[t], acc, 0, 0, 0);
      acc = __builtin_amdgcn_mfma_f32_32x32x16_bf16(al, wbh[t], acc, 0, 0, 0);
    }
    if (kh == 0) __syncthreads();  // all reads done before buffer reuse
  }

  int j = wv * 32 + fm;
  float bv = bias[j];
#pragma unroll
  for (int r = 0; r < 16; r++) {
    int row = (r & 3) + 8 * (r >> 2) + 4 * fq;
    int node = node0 + row;
    if (node < N_NODES)
      OutT[(size_t)node * D + j] = f2bf((acc[r] + bv) * dinvp[node]);
  }
}

// ---------------- branch-free group gather ----------------
// 16 lanes = 1 node; lane h owns dims h*8..h*8+7 (one uint4).
// A single 16-deep burst covers P(deg<=16)~=0.9 of rows in ONE round-trip;
// short rows are padded with the zeroed dummy row at index N_NODES
// (L1-resident, adds 0.0). No divergent ladder, no serial sub-bursts.
__device__ __forceinline__ void addu4(float acc[8], uint4 u) {
  acc[0] += bflo(u.x);
  acc[1] += bfhi(u.x);
  acc[2] += bflo(u.y);
  acc[3] += bfhi(u.y);
  acc[4] += bflo(u.z);
  acc[5] += bfhi(u.z);
  acc[6] += bflo(u.w);
  acc[7] += bfhi(u.w);
}

__device__ __forceinline__ void burst16(const uint4* __restrict__ tu4, int sidx,
                                        int gbase, int h, float acc[8]) {
  uint4 u[16];
#pragma unroll
  for (int q = 0; q < 16; q++) {
    int s = __shfl(sidx, gbase + q);  // lanes beyond row length hold N_NODES
    u[q] = tu4[(size_t)s * 16 + h];
  }
#pragma unroll
  for (int q = 0; q < 16; q++) addu4(acc, u[q]);
}

__device__ __forceinline__ void agg_tail(const uint4* __restrict__ tu4,
                                         const int* __restrict__ csr,
                                         int e0, int e1, int gbase, int h,
                                         float acc[8]) {
  for (int b2 = e0 + 16; b2 < e1; b2 += 16) {  // rare: deg > 16
    int c2 = e1 - b2;
    int sx = (h < c2) ? csr[b2 + h] : N_NODES;
    burst16(tu4, sx, gbase, h, acc);
  }
}

// ---------------- FUSED aggregate1 + conv2-GEMM ----------------
__global__ __launch_bounds__(256) void k_agg_gemm(
    const ushort_t* __restrict__ t1, const int* __restrict__ row_start,
    const int* __restrict__ csr, const float* __restrict__ dinv,
    const float* __restrict__ b1f,
    const ushort_t* __restrict__ Wsw, ushort_t* __restrict__ OutT2) {
  constexpr int XS = 136;
  __shared__ __align__(16) ushort_t xh_lds[32 * XS];
  __shared__ __align__(16) ushort_t xl_lds[32 * XS];

  int tid = threadIdx.x;
  int lane = tid & 63;
  int wv = tid >> 6;
  int node0 = blockIdx.x * 32;
  int fm = lane & 31;
  int fq = lane >> 5;
  int g = lane >> 4;   // group 0..3
  int h = lane & 15;   // dim-chunk 0..15
  int gbase = lane & 48;

  const uint4* tu4 = (const uint4*)t1;
  float4 bA = *(const float4*)&b1f[h * 8];
  float4 bB = *(const float4*)&b1f[h * 8 + 4];

  // ---- hoist ALL per-wave random loads to the top (concurrent RTs) ----
  int node0w = node0 + wv * 8;
  int rsv = row_start[min(node0w + min(lane, 8), N_NODES)];
  float dvl = dinv[min(node0w + min(lane, 7), N_NODES - 1)];

  int nodeA = node0w + g;      // pass-0 node (wave rows 0..3)
  int nodeB = node0w + 4 + g;  // pass-1 node (wave rows 4..7)
  int e0A = __shfl(rsv, g), e1A = __shfl(rsv, g + 1);
  int e0B = __shfl(rsv, 4 + g), e1B = __shfl(rsv, 5 + g);
  int cntA = e1A - e0A, cntB = e1B - e0B;  // OOB nodes give cnt=0 via clamp
  bool vA = nodeA < N_NODES, vB = nodeB < N_NODES;

  int sidxA = (h < cntA) ? csr[e0A + h] : N_NODES;
  int sidxB = (h < cntB) ? csr[e0B + h] : N_NODES;
  uint4 usA = tu4[(size_t)(vA ? nodeA : N_NODES) * 16 + h];  // self-loop rows
  uint4 usB = tu4[(size_t)(vB ? nodeB : N_NODES) * 16 + h];
  float diA = __shfl(dvl, g);
  float diB = __shfl(dvl, 4 + g);

  // ---- pass A ----
  float accA[8];
#pragma unroll
  for (int q = 0; q < 8; q++) accA[q] = 0.f;
  addu4(accA, usA);
  burst16(tu4, sidxA, gbase, h, accA);
  agg_tail(tu4, csr, e0A, e1A, gbase, h, accA);

  // ---- pass B (csr indices + self row already in flight) ----
  float accB[8];
#pragma unroll
  for (int q = 0; q < 8; q++) accB[q] = 0.f;
  addu4(accB, usB);
  burst16(tu4, sidxB, gbase, h, accB);
  agg_tail(tu4, csr, e0B, e1B, gbase, h, accB);

  // ---- epilogues -> LDS ----
#pragma unroll
  for (int p = 0; p < 2; p++) {
    float* acc = p ? accB : accA;
    bool vv = p ? vB : vA;
    float di = p ? diB : diA;
    int row = wv * 8 + p * 4 + g;
    bf16x8 ph, pl;
    if (vv) {
      float val[8];
      val[0] = fmaxf(di * acc[0] + bA.x, 0.f);
      val[1] = fmaxf(di * acc[1] + bA.y, 0.f);
      val[2] = fmaxf(di * acc[2] + bA.z, 0.f);
      val[3] = fmaxf(di * acc[3] + bA.w, 0.f);
      val[4] = fmaxf(di * acc[4] + bB.x, 0.f);
      val[5] = fmaxf(di * acc[5] + bB.y, 0.f);
      val[6] = fmaxf(di * acc[6] + bB.z, 0.f);
      val[7] = fmaxf(di * acc[7] + bB.w, 0.f);
#pragma unroll
      for (int q = 0; q < 8; q++) {
        ushort_t hq = f2bf(val[q]);
        ph[q] = (short)hq;
        pl[q] = (short)f2bf(val[q] - bf2f(hq));
      }
    } else {
#pragma unroll
      for (int q = 0; q < 8; q++) { ph[q] = 0; pl[q] = 0; }
    }
    *(bf16x8*)&xh_lds[row * XS + h * 8] = ph;
    *(bf16x8*)&xl_lds[row * XS + h * 8] = pl;
  }
  __syncthreads();

  f32x16 acc;
#pragma unroll
  for (int r = 0; r < 16; r++) acc[r] = 0.f;
  {
    const ushort_t* wb = Wsw + ((size_t)wv * 8) * 2 * 512 + lane * 8;
    bf16x8 wbh[8], wbl[8];
#pragma unroll
    for (int t = 0; t < 8; t++) {
      wbh[t] = *(const bf16x8*)(wb + (size_t)t * 1024);
      wbl[t] = *(const bf16x8*)(wb + (size_t)t * 1024 + 512);
    }
#pragma unroll
    for (int t = 0; t < 8; t++) {
      int ko = t * 16 + fq * 8;
      bf16x8 ah = *(const bf16x8*)&xh_lds[fm * XS + ko];
      bf16x8 al = *(const bf16x8*)&xl_lds[fm * XS + ko];
      acc = __builtin_amdgcn_mfma_f32_32x32x16_bf16(ah, wbh[t], acc, 0, 0, 0);
      acc = __builtin_amdgcn_mfma_f32_32x32x16_bf16(ah, wbl[t], acc, 0, 0, 0);
      acc = __builtin_amdgcn_mfma_f32_32x32x16_bf16(al, wbh[t], acc, 0, 0, 0);
    }
  }
  int j = wv * 32 + fm;
#pragma unroll
  for (int r = 0; r < 16; r++) {
    int row = (r & 3) + 8 * (r >> 2) + 4 * fq;
    int node = node0 + row;
    if (node < N_NODES)
      OutT2[(size_t)node * D + j] = f2bf(acc[r] * dinv[node]);
  }
}

// ---------------- final aggregation -> fp32 out ----------------
// 4 nodes per wave, 16 per block; same hoisted branch-free gather.
__global__ __launch_bounds__(256) void k_aggregate_out(
    const ushort_t* __restrict__ t, const int* __restrict__ row_start,
    const int* __restrict__ csr, const float* __restrict__ dinv,
    const float* __restrict__ bias, float* __restrict__ out_f) {
  int wv = threadIdx.x >> 6;
  int lane = threadIdx.x & 63;
  int g = lane >> 4;
  int h = lane & 15;
  int gbase = lane & 48;
  int nodew = blockIdx.x * 16 + wv * 4;
  int rsv = row_start[min(nodew + min(lane, 4), N_NODES)];
  float dvl = dinv[min(nodew + min(lane, 3), N_NODES - 1)];
  int node = nodew + g;
  int e0 = __shfl(rsv, g), e1 = __shfl(rsv, g + 1);
  int cnt = e1 - e0;
  bool vn = node < N_NODES;

  const uint4* tu4 = (const uint4*)t;
  int sidx = (h < cnt) ? csr[e0 + h] : N_NODES;
  uint4 us = tu4[(size_t)(vn ? node : N_NODES) * 16 + h];
  float di = __shfl(dvl, g);

  float acc[8];
#pragma unroll
  for (int q = 0; q < 8; q++) acc[q] = 0.f;
  addu4(acc, us);
  burst16(tu4, sidx, gbase, h, acc);
  agg_tail(tu4, csr, e0, e1, gbase, h, acc);

  if (!vn) return;
  float4 bA = *(const float4*)&bias[h * 8];
  float4 bB = *(const float4*)&bias[h * 8 + 4];
  float4 o0, o1;
  o0.x = di * acc[0] + bA.x;
  o0.y = di * acc[1] + bA.y;
  o0.z = di * acc[2] + bA.z;
  o0.w = di * acc[3] + bA.w;
  o1.x = di * acc[4] + bB.x;
  o1.y = di * acc[5] + bB.y;
  o1.z = di * acc[6] + bB.z;
  o1.w = di * acc[7] + bB.w;
  *(float4*)&out_f[(size_t)node * D + h * 8] = o0;
  *(float4*)&out_f[(size_t)node * D + h * 8 + 4] = o1;
}

extern "C" void kernel_launch(void* const* d_in, const int* in_sizes, int n_in,
                              void* d_out, int out_size, void* d_ws, size_t ws_size,
                              hipStream_t stream) {
  const int* tokens = (const int*)d_in[0];
  const int* edge = (const int*)d_in[1];  // [2][E]
  const float* embed = (const float*)d_in[2];
  const float* Wn = (const float*)d_in[3];
  const float* bn = (const float*)d_in[4];
  const float* w1 = (const float*)d_in[5];
  const float* b1 = (const float*)d_in[6];
  const float* w2 = (const float*)d_in[7];
  const float* b2 = (const float*)d_in[8];
  float* out = (float*)d_out;  // fp32 output

  const int* src = edge;
  const int* dst = edge + N_EDGES;

  char* ws = (char*)d_ws;
  // T1/T2 have one extra ZERO row at index N_NODES (gather padding target)
  ushort_t* T1 = (ushort_t*)ws;                    // 12,800,256 B
  ushort_t* T2 = (ushort_t*)(ws + 12800256);       // 12,800,256 B
  int* epos = (int*)(ws + 25600512);               // 2,400,000 B (edge slot)
  float* dinv = (float*)(ws + 28000512);           // 200,000 B
  int* row_start = (int*)(ws + 28200512);          // 200,004 B
  int* deg = (int*)(ws + 28400576);                // 200,000 B
  int* csr = (int*)(ws + 28600576);                // 2,400,000 B
  int* partial = (int*)(ws + 31000576);            // 196 B
  ushort_t* WcSw = (ushort_t*)(ws + 31000832);     // 131,072 B (swizzled hi/lo)
  ushort_t* W2Sw = (ushort_t*)(ws + 31131904);     // 65,536 B (swizzled hi/lo)
  float* bias_ws = (float*)(ws + 31197440);        // bc | b1 | b2 (1,536 B)
  float* bcf = bias_ws;
  float* b1f = bias_ws + 128;
  float* b2f = bias_ws + 256;

  // --- zero deg; prep + degree count (emits per-edge CSR slot) ---
  hipMemsetAsync(deg, 0, N_NODES * sizeof(int), stream);
  k_prep_deg<<<193 + EDGE_BLOCKS, 256, 0, stream>>>(
      Wn, w1, bn, w2, b1, b2, dst, WcSw, bcf, W2Sw, b1f, b2f, deg, epos);

  // --- CSR scan (+ dummy-row zeroing) ---
  k_partial<<<N_CHUNKS, 256, 0, stream>>>(deg, partial);
  k_scan_final<<<N_CHUNKS, 256, 0, stream>>>(deg, partial, row_start, dinv, T1, T2);

  // --- merged: conv1 T1 = (gather(e)@Wc^T + bc)*dinv  ||  CSR fill ---
  k_gemm_fill<<<GEMM_BLOCKS + EDGE_BLOCKS, 256, 0, stream>>>(
      embed, tokens, WcSw, bcf, dinv, T1, src, dst, row_start, epos, csr);

  // --- fused: x1 = relu(agg(T1)+b1); T2 = (x1 @ w2^T)*dinv ---
  k_agg_gemm<<<GEMM_BLOCKS, 256, 0, stream>>>(
      T1, row_start, csr, dinv, b1f, W2Sw, T2);

  // --- final aggregate + b2 -> out (fp32) ---
  k_aggregate_out<<<(N_NODES + 15) / 16, 256, 0, stream>>>(
      T2, row_start, csr, dinv, b2f, out);
}